// Round 3
// baseline (182.602 us; speedup 1.0000x reference)
//
#include <hip/hip_runtime.h>
#include <hip/hip_bf16.h>

#define B_ 8
#define N_ 1024
#define F_ 256
#define OUT_ 256
#define REL_ 16
#define NADJ_ 7

typedef __attribute__((ext_vector_type(8))) _Float16 f16x8;
typedef __attribute__((ext_vector_type(4))) _Float16 f16x4;
typedef __attribute__((ext_vector_type(4))) float f32x4;

__device__ __forceinline__ void gll16(const _Float16* g, _Float16* l) {
    __builtin_amdgcn_global_load_lds(
        (const __attribute__((address_space(1))) void*)g,
        (__attribute__((address_space(3))) void*)l, 16, 0, 0);
}

__device__ __forceinline__ f16x8 cvt8(float4 a, float4 b) {
    return f16x8{(_Float16)a.x, (_Float16)a.y, (_Float16)a.z, (_Float16)a.w,
                 (_Float16)b.x, (_Float16)b.y, (_Float16)b.z, (_Float16)b.w};
}

// perm order: rr 0..3 = r{0,1,3,4} (real adjacency), 4..6 = r{2,5,6} (identity adjacency)
__constant__ const int c_perm[7] = {0, 1, 3, 4, 2, 5, 6};

// ---------------- prep: cbias (blocks 0..6) | transW (7..1798) | cvt feat (1799..2822) ---
__global__ __launch_bounds__(256) void prep_kernel(const float* __restrict__ W,
                                                   const float* __restrict__ We,
                                                   const float* __restrict__ feat,
                                                   float* __restrict__ cb,
                                                   _Float16* __restrict__ WTp,
                                                   _Float16* __restrict__ Fe) {
    int bid = blockIdx.x, tid = threadIdx.x;
    if (bid < 7) {
        int idx = bid * 256 + tid;
        int j = idx / OUT_, o = idx % OUT_;
        int r = c_perm[j];
        const float* Wr = W + (size_t)r * (F_ + REL_) * OUT_;
        float s = 0.f;
#pragma unroll
        for (int d = 0; d < REL_; ++d) s += We[r * REL_ + d] * Wr[(F_ + d) * OUT_ + o];
        cb[idx] = s;
    } else if (bid < 1799) {
        int idx = (bid - 7) * 256 + tid;  // 7*65536 total
        int j = idx >> 16, rem = idx & 65535, o = rem >> 8, f = rem & 255;
        int r = c_perm[j];
        WTp[idx] = (_Float16)W[((size_t)r * (F_ + REL_) + f) * OUT_ + o];
    } else {
        int i = (bid - 1799) * 256 + tid;  // 262144 groups of 8
        size_t base = (size_t)i * 8;
        float4 a = *(const float4*)(feat + base);
        float4 b = *(const float4*)(feat + base + 4);
        *(f16x8*)(Fe + base) = cvt8(a, b);
    }
}

// ======= hw7: HW GEMMs, 2-phase double-buffered.
// blocks [0,512): z<4: HWT[z][o][m] = (Fe @ W[z])^T + cb
// blocks [512,640): merged identity z=4,5,6: HWNmax[m][o] = max_z(Fe @ W[z] + cb[z])
__global__ __launch_bounds__(256) void hw7_kernel(const _Float16* __restrict__ Fe,
                                                  const _Float16* __restrict__ WTp,
                                                  const float* __restrict__ cb,
                                                  _Float16* __restrict__ HWT,
                                                  _Float16* __restrict__ HWNm) {
    __shared__ _Float16 S[2 * 8192];  // buf c: As = S+c*8192, Bs = As+4096 (BK=32)
    const int bid = blockIdx.x, tid = threadIdx.x;
    const int wave = tid >> 6, lane = tid & 63, lm = lane & 15, q = lane >> 4;
    const int wr = (wave >> 1) * 64, wc = (wave & 1) * 64;
    const int srow = tid >> 2, sk = (tid & 3) * 8;

    f32x4 acc[4][4] = {};

    auto mfma_step = [&](const _Float16* Au, const _Float16* Bu) {
        f16x8 af[4], bf[4];
#pragma unroll
        for (int i = 0; i < 4; ++i) af[i] = *(const f16x8*)(Au + (wr + i * 16 + lm) * 32 + q * 8);
#pragma unroll
        for (int j = 0; j < 4; ++j) bf[j] = *(const f16x8*)(Bu + (wc + j * 16 + lm) * 32 + q * 8);
#pragma unroll
        for (int i = 0; i < 4; ++i)
#pragma unroll
            for (int j = 0; j < 4; ++j)
                acc[i][j] = __builtin_amdgcn_mfma_f32_16x16x32_f16(af[i], bf[j], acc[i][j], 0, 0, 0);
    };

    if (bid < 512) {
        const int z = bid >> 7, rem = bid & 127, bx = rem & 63, by = rem >> 6;
        // z<4: A = WTp[z] (rows o), B = Fe (rows m) -> C[o][m]
        const _Float16* A  = WTp + (size_t)z * 65536;
        const _Float16* Bt = Fe;
        const int m0 = by * 128;   // o-tile
        const int n0 = bx * 128;   // m-tile
        const _Float16* ga0 = A + (size_t)(m0 + srow) * F_ + sk;
        const _Float16* ga1 = ga0 + (size_t)64 * F_;
        const _Float16* gb0 = Bt + (size_t)(n0 + srow) * F_ + sk;
        const _Float16* gb1 = gb0 + (size_t)64 * F_;
        // prologue: stage step 0 into buf0
        gll16(ga0, S + tid * 8);
        gll16(ga1, S + 2048 + tid * 8);
        gll16(gb0, S + 4096 + tid * 8);
        gll16(gb1, S + 6144 + tid * 8);
        __syncthreads();
        for (int t = 0; t < 8; ++t) {
            const int c = t & 1, n = c ^ 1;
            if (t < 7) {
                const int k = (t + 1) * 32;
                _Float16* base = S + n * 8192;
                gll16(ga0 + k, base + tid * 8);
                gll16(ga1 + k, base + 2048 + tid * 8);
                gll16(gb0 + k, base + 4096 + tid * 8);
                gll16(gb1 + k, base + 6144 + tid * 8);
            }
            mfma_step(S + c * 8192, S + c * 8192 + 4096);
            __syncthreads();
        }
        const float* cbz = cb + (size_t)z * 256;
        _Float16* C = HWT + (size_t)z * ((size_t)256 * 8192);
#pragma unroll
        for (int i = 0; i < 4; ++i)
#pragma unroll
            for (int j = 0; j < 4; ++j)
#pragma unroll
                for (int g = 0; g < 4; ++g) {
                    int row = wr + i * 16 + q * 4 + g;   // o
                    int col = wc + j * 16 + lm;          // m
                    float v = acc[i][j][g] + cbz[m0 + row];
                    C[(size_t)(m0 + row) * 8192 + (n0 + col)] = (_Float16)v;
                }
    } else {
        // merged identity relations: 3 passes over zi=4,5,6, shared A = Fe
        const int idx = bid - 512, bx = idx & 63, by = idx >> 6;
        const int m0 = bx * 128;   // m-tile
        const int n0 = by * 128;   // o-tile
        const _Float16* ga0 = Fe + (size_t)(m0 + srow) * F_ + sk;
        const _Float16* ga1 = ga0 + (size_t)64 * F_;
        float mx[4][4][4];
#pragma unroll
        for (int i = 0; i < 4; ++i)
#pragma unroll
            for (int j = 0; j < 4; ++j)
#pragma unroll
                for (int g = 0; g < 4; ++g) mx[i][j][g] = -1e30f;
#pragma unroll 1
        for (int zi = 4; zi < 7; ++zi) {
            const _Float16* gb0 = WTp + (size_t)zi * 65536 + (size_t)(n0 + srow) * F_ + sk;
            const _Float16* gb1 = gb0 + (size_t)64 * F_;
#pragma unroll
            for (int i = 0; i < 4; ++i)
#pragma unroll
                for (int j = 0; j < 4; ++j) acc[i][j] = f32x4{0.f, 0.f, 0.f, 0.f};
            gll16(ga0, S + tid * 8);
            gll16(ga1, S + 2048 + tid * 8);
            gll16(gb0, S + 4096 + tid * 8);
            gll16(gb1, S + 6144 + tid * 8);
            __syncthreads();
            for (int t = 0; t < 8; ++t) {
                const int c = t & 1, n = c ^ 1;
                if (t < 7) {
                    const int k = (t + 1) * 32;
                    _Float16* base = S + n * 8192;
                    gll16(ga0 + k, base + tid * 8);
                    gll16(ga1 + k, base + 2048 + tid * 8);
                    gll16(gb0 + k, base + 4096 + tid * 8);
                    gll16(gb1 + k, base + 6144 + tid * 8);
                }
                mfma_step(S + c * 8192, S + c * 8192 + 4096);
                __syncthreads();
            }
            const float* cbz = cb + (size_t)zi * 256;
#pragma unroll
            for (int i = 0; i < 4; ++i)
#pragma unroll
                for (int j = 0; j < 4; ++j)
#pragma unroll
                    for (int g = 0; g < 4; ++g) {
                        int col = wc + j * 16 + lm;  // o
                        mx[i][j][g] = fmaxf(mx[i][j][g], acc[i][j][g] + cbz[n0 + col]);
                    }
        }
#pragma unroll
        for (int i = 0; i < 4; ++i)
#pragma unroll
            for (int j = 0; j < 4; ++j)
#pragma unroll
                for (int g = 0; g < 4; ++g) {
                    int row = wr + i * 16 + q * 4 + g;   // m
                    int col = wc + j * 16 + lm;          // o
                    HWNm[(size_t)(m0 + row) * 256 + (n0 + col)] = (_Float16)mx[i][j][g];
                }
    }
}

// ======= phase2: AHW[kh][rr][b][n][o] partial = A_rr[b][khalf] @ HWT-half^T =======
// Grid 1024: K-split x2 (kh), 128x128 tiles, BK=32, 2-phase double-buffered LDS
// (one __syncthreads per k-step; staging for step t+1 overlaps MFMA of step t).
// XCD-aware remap: 16 blocks of a (zz,kh) group land on one XCD (B strip + A tiles L2-shared).
// As layout: element (m,k) at As[m*32 + (k ^ (((m>>4)&3)<<3))] (granule-8 XOR swizzle).
__global__ __launch_bounds__(256) void p2_kernel(const float* __restrict__ A1,
                                                 const float* __restrict__ A2,
                                                 const _Float16* __restrict__ HWT,
                                                 _Float16* __restrict__ AHW) {
    __shared__ _Float16 As[2 * 4096];
    __shared__ _Float16 Bs[2 * 4096];
    const int d = blockIdx.x;
    const int xcd = d & 7, slot = d >> 3;
    const int Ghi = xcd + 8 * (slot >> 4);      // [0,64): (zz,kh) group
    const int member = (slot >> 3) & 1;         // o/n-tile
    const int mt = slot & 7;                    // m-tile
    const int kh = Ghi & 1;                     // K half
    const int zz = Ghi >> 1;                    // rr*8+b
    const int rr = zz >> 3, b = zz & 7;

    const size_t slab = (size_t)B_ * N_ * OUT_;
    const _Float16* Bt = HWT + (size_t)rr * (256 * 8192) + (size_t)b * 1024;
    _Float16* C = AHW + (size_t)kh * (4 * slab) + (size_t)rr * slab + (size_t)b * (N_ * OUT_);
    const int m0 = mt * 128, n0 = member * 128, kbase = kh * 512;
    const int tid = threadIdx.x;
    const int wave = tid >> 6, lane = tid & 63, lm = lane & 15, q = lane >> 4;
    const int wr = (wave >> 1) * 64, wc = (wave & 1) * 64;
    const int srow = tid >> 2, sk = (tid & 3) * 8;
    const _Float16* gb0 = Bt + (size_t)(n0 + srow) * 8192 + kbase + sk;
    const _Float16* gb1 = gb0 + (size_t)64 * 8192;

    const float* Ag = ((rr & 1) ? A2 : A1) + (size_t)b * N_ * N_;
    f32x4 acc[4][4] = {};

    auto mfma_step = [&](int c) {
        const _Float16* Au = As + c * 4096;
        const _Float16* Bu = Bs + c * 4096;
        f16x8 af[4], bf[4];
#pragma unroll
        for (int i = 0; i < 4; ++i)
            af[i] = *(const f16x8*)(Au + (wr + i * 16 + lm) * 32 + ((q ^ i) * 8));
#pragma unroll
        for (int j = 0; j < 4; ++j)
            bf[j] = *(const f16x8*)(Bu + (wc + j * 16 + lm) * 32 + q * 8);
#pragma unroll
        for (int i = 0; i < 4; ++i)
#pragma unroll
            for (int j = 0; j < 4; ++j)
                acc[i][j] = __builtin_amdgcn_mfma_f32_16x16x32_f16(af[i], bf[j], acc[i][j], 0, 0, 0);
    };

    if (rr < 2) {
        // straight: As[m][k] = Ag[m0+m][kbase + t*32 + k]
        const float* Ag0 = Ag + (size_t)(m0 + srow) * N_ + kbase + sk;
        const float* Ag1 = Ag0 + (size_t)64 * N_;
        const int sx = ((tid & 3) ^ ((tid >> 6) & 3)) * 8;
        float4 pa = *(const float4*)(Ag0);
        float4 pb = *(const float4*)(Ag0 + 4);
        float4 pc = *(const float4*)(Ag1);
        float4 pd = *(const float4*)(Ag1 + 4);
        // prologue: stage step 0 into buf0
        *(f16x8*)(As + srow * 32 + sx) = cvt8(pa, pb);
        *(f16x8*)(As + 2048 + srow * 32 + sx) = cvt8(pc, pd);
        gll16(gb0, Bs + tid * 8);
        gll16(gb1, Bs + 2048 + tid * 8);
        pa = *(const float4*)(Ag0 + 32); pb = *(const float4*)(Ag0 + 36);
        pc = *(const float4*)(Ag1 + 32); pd = *(const float4*)(Ag1 + 36);
        __syncthreads();
        for (int t = 0; t < 16; ++t) {
            const int c = t & 1, n = c ^ 1;
            if (t < 15) {
                _Float16* la = As + n * 4096 + srow * 32 + sx;
                *(f16x8*)(la) = cvt8(pa, pb);
                *(f16x8*)(la + 2048) = cvt8(pc, pd);
                gll16(gb0 + (t + 1) * 32, Bs + n * 4096 + tid * 8);
                gll16(gb1 + (t + 1) * 32, Bs + n * 4096 + 2048 + tid * 8);
                if (t < 14) {
                    const int k = (t + 2) * 32;
                    pa = *(const float4*)(Ag0 + k); pb = *(const float4*)(Ag0 + k + 4);
                    pc = *(const float4*)(Ag1 + k); pd = *(const float4*)(Ag1 + k + 4);
                }
            }
            mfma_step(c);
            __syncthreads();
        }
    } else {
        // transposed: As[m][k] = Ag[kbase + t*32 + k][m0+m]; coalesced k-row reads,
        // b64 scatter into swizzled LDS. Thread: k-rows kk4..+3, cols ms4..+3.
        const int kk4 = (tid >> 5) * 4;          // 0..28
        const int ms4 = (tid & 31) * 4;          // 0..124
        const int tsw = ((ms4 >> 4) & 3) << 3;
        const int wof = ms4 * 32 + (kk4 ^ tsw);
        const float* gA = Ag + (size_t)(kbase + kk4) * N_ + m0 + ms4;
        float4 ra0 = *(const float4*)(gA);
        float4 ra1 = *(const float4*)(gA + N_);
        float4 ra2 = *(const float4*)(gA + 2 * N_);
        float4 ra3 = *(const float4*)(gA + 3 * N_);
        // prologue: stage step 0 into buf0
        {
            _Float16* wp = As + wof;
            *(f16x4*)(wp + 0 * 32) = f16x4{(_Float16)ra0.x, (_Float16)ra1.x, (_Float16)ra2.x, (_Float16)ra3.x};
            *(f16x4*)(wp + 1 * 32) = f16x4{(_Float16)ra0.y, (_Float16)ra1.y, (_Float16)ra2.y, (_Float16)ra3.y};
            *(f16x4*)(wp + 2 * 32) = f16x4{(_Float16)ra0.z, (_Float16)ra1.z, (_Float16)ra2.z, (_Float16)ra3.z};
            *(f16x4*)(wp + 3 * 32) = f16x4{(_Float16)ra0.w, (_Float16)ra1.w, (_Float16)ra2.w, (_Float16)ra3.w};
        }
        gll16(gb0, Bs + tid * 8);
        gll16(gb1, Bs + 2048 + tid * 8);
        {
            const float* p = gA + (size_t)32 * N_;
            ra0 = *(const float4*)(p);
            ra1 = *(const float4*)(p + N_);
            ra2 = *(const float4*)(p + 2 * N_);
            ra3 = *(const float4*)(p + 3 * N_);
        }
        __syncthreads();
        for (int t = 0; t < 16; ++t) {
            const int c = t & 1, n = c ^ 1;
            if (t < 15) {
                _Float16* wp = As + n * 4096 + wof;
                *(f16x4*)(wp + 0 * 32) = f16x4{(_Float16)ra0.x, (_Float16)ra1.x, (_Float16)ra2.x, (_Float16)ra3.x};
                *(f16x4*)(wp + 1 * 32) = f16x4{(_Float16)ra0.y, (_Float16)ra1.y, (_Float16)ra2.y, (_Float16)ra3.y};
                *(f16x4*)(wp + 2 * 32) = f16x4{(_Float16)ra0.z, (_Float16)ra1.z, (_Float16)ra2.z, (_Float16)ra3.z};
                *(f16x4*)(wp + 3 * 32) = f16x4{(_Float16)ra0.w, (_Float16)ra1.w, (_Float16)ra2.w, (_Float16)ra3.w};
                gll16(gb0 + (t + 1) * 32, Bs + n * 4096 + tid * 8);
                gll16(gb1 + (t + 1) * 32, Bs + n * 4096 + 2048 + tid * 8);
                if (t < 14) {
                    const float* p = gA + (size_t)(t + 2) * 32 * N_;
                    ra0 = *(const float4*)(p);
                    ra1 = *(const float4*)(p + N_);
                    ra2 = *(const float4*)(p + 2 * N_);
                    ra3 = *(const float4*)(p + 3 * N_);
                }
            }
            mfma_step(c);
            __syncthreads();
        }
    }
#pragma unroll
    for (int i = 0; i < 4; ++i)
#pragma unroll
        for (int j = 0; j < 4; ++j)
#pragma unroll
            for (int g = 0; g < 4; ++g) {
                int row = wr + i * 16 + q * 4 + g;
                int col = wc + j * 16 + lm;
                C[(size_t)(m0 + row) * 256 + (n0 + col)] = (_Float16)acc[i][j][g];
            }
}

// ======= final: out = max(AHW_h0+AHW_h1 over rr, HWNmax) + bias =======
__global__ __launch_bounds__(256) void max_kernel(const _Float16* __restrict__ AHW,
                                                  const _Float16* __restrict__ HWNm,
                                                  const float* __restrict__ bias,
                                                  float* __restrict__ out) {
    size_t i = ((size_t)blockIdx.x * 256 + threadIdx.x) * 8;
    const size_t slab = (size_t)B_ * N_ * OUT_;
    const size_t HS = 4 * slab;
    float m[8];
    {
        f16x8 v0 = *(const f16x8*)(AHW + i);
        f16x8 v1 = *(const f16x8*)(AHW + HS + i);
#pragma unroll
        for (int e = 0; e < 8; ++e) m[e] = (float)v0[e] + (float)v1[e];
    }
#pragma unroll
    for (int rr = 1; rr < 4; ++rr) {
        f16x8 v0 = *(const f16x8*)(AHW + rr * slab + i);
        f16x8 v1 = *(const f16x8*)(AHW + HS + rr * slab + i);
#pragma unroll
        for (int e = 0; e < 8; ++e) m[e] = fmaxf(m[e], (float)v0[e] + (float)v1[e]);
    }
    {
        f16x8 w = *(const f16x8*)(HWNm + i);
#pragma unroll
        for (int e = 0; e < 8; ++e) m[e] = fmaxf(m[e], (float)w[e]);
    }
    size_t bidx = i & ((size_t)N_ * OUT_ - 1);
    float4 b0 = *(const float4*)(bias + bidx);
    float4 b1 = *(const float4*)(bias + bidx + 4);
    float4 o0 = {m[0] + b0.x, m[1] + b0.y, m[2] + b0.z, m[3] + b0.w};
    float4 o1 = {m[4] + b1.x, m[5] + b1.y, m[6] + b1.z, m[7] + b1.w};
    *(float4*)(out + i) = o0;
    *(float4*)(out + i + 4) = o1;
}

// ======================= round-1 fallback path (ws too small) ===========================
__global__ void cbias_kernel(const float* __restrict__ W, const float* __restrict__ We,
                             float* __restrict__ c) {
    int idx = blockIdx.x * 256 + threadIdx.x;
    if (idx >= NADJ_ * OUT_) return;
    int r = idx / OUT_, o = idx % OUT_;
    const float* Wr = W + (size_t)r * (F_ + REL_) * OUT_;
    float s = 0.f;
#pragma unroll
    for (int d = 0; d < REL_; ++d) s += We[r * REL_ + d] * Wr[(F_ + d) * OUT_ + o];
    c[idx] = s;
}

__global__ __launch_bounds__(256) void hw_kernel(const float* __restrict__ feat,
                                                 const float* __restrict__ W,
                                                 const float* __restrict__ cb,
                                                 _Float16* __restrict__ HWb) {
    __shared__ _Float16 As[64][32];
    __shared__ _Float16 Bs[64][32];
    const int mt = blockIdx.x, ct = blockIdx.y;
    const int tid = threadIdx.x, wave = tid >> 6, lane = tid & 63;
    const int r = (ct * 64) / OUT_;
    const int o0 = (ct * 64) % OUT_;
    const float* Bg = W + (size_t)r * (F_ + REL_) * OUT_ + o0;
    const int m0 = mt * 64;
    const int lm = lane & 15, q = lane >> 4;
    f32x4 acc[4] = {};
    for (int k0 = 0; k0 < F_; k0 += 32) {
        {
            int seg = (tid & 3) * 8, m = tid >> 2;
            const float* src = feat + (size_t)(m0 + m) * F_ + k0 + seg;
#pragma unroll
            for (int j = 0; j < 8; ++j) As[m][seg + j] = (_Float16)src[j];
        }
        {
            int kk = tid >> 3, ns = (tid & 7) * 8;
            const float* src = Bg + (size_t)(k0 + kk) * OUT_ + ns;
#pragma unroll
            for (int j = 0; j < 8; ++j) Bs[ns + j][kk] = (_Float16)src[j];
        }
        __syncthreads();
        f16x8 a = *(const f16x8*)&As[wave * 16 + lm][q * 8];
#pragma unroll
        for (int c4 = 0; c4 < 4; ++c4) {
            f16x8 b = *(const f16x8*)&Bs[c4 * 16 + lm][q * 8];
            acc[c4] = __builtin_amdgcn_mfma_f32_16x16x32_f16(a, b, acc[c4], 0, 0, 0);
        }
        __syncthreads();
    }
#pragma unroll
    for (int c4 = 0; c4 < 4; ++c4)
#pragma unroll
        for (int g = 0; g < 4; ++g) {
            int row = wave * 16 + (lane >> 4) * 4 + g;
            int col = c4 * 16 + lm;
            float v = acc[c4][g] + cb[r * OUT_ + o0 + col];
            HWb[((size_t)r * B_ * N_ + m0 + row) * OUT_ + o0 + col] = (_Float16)v;
        }
}

__global__ __launch_bounds__(256) void agg_kernel(const float* __restrict__ A1,
                                                  const float* __restrict__ A2,
                                                  const _Float16* __restrict__ HWb,
                                                  const float* __restrict__ bias,
                                                  float* __restrict__ out) {
    __shared__ _Float16 As[64][32];
    __shared__ _Float16 Bs[64][32];
    const int b = blockIdx.z, nt = blockIdx.y, ot = blockIdx.x;
    const int tid = threadIdx.x, wave = tid >> 6, lane = tid & 63;
    const int n0 = nt * 64, o0 = ot * 64;
    const int lm = lane & 15, q = lane >> 4;
    const size_t rstride = (size_t)B_ * N_ * OUT_;
    f32x4 mx[4];
#pragma unroll
    for (int i = 0; i < 4; ++i) mx[i] = f32x4{-1e30f, -1e30f, -1e30f, -1e30f};
#pragma unroll 1
    for (int rr = 0; rr < 4; ++rr) {
        const float* Ag = ((rr & 1) ? A2 : A1) + (size_t)b * N_ * N_;
        const bool tr = (rr >= 2);
        const int r = (rr < 2) ? rr : rr + 1;
        const _Float16* Bg = HWb + (size_t)r * rstride + (size_t)b * N_ * OUT_ + o0;
        f32x4 acc[4] = {};
        for (int k0 = 0; k0 < N_; k0 += 32) {
            if (!tr) {
                int seg = (tid & 3) * 8, m = tid >> 2;
                const float* src = Ag + (size_t)(n0 + m) * N_ + k0 + seg;
#pragma unroll
                for (int j = 0; j < 8; ++j) As[m][seg + j] = (_Float16)src[j];
            } else {
                int kk = tid >> 3, ms = (tid & 7) * 8;
                const float* src = Ag + (size_t)(k0 + kk) * N_ + n0 + ms;
#pragma unroll
                for (int j = 0; j < 8; ++j) As[ms + j][kk] = (_Float16)src[j];
            }
            {
                int kk = tid >> 3, ns = (tid & 7) * 8;
                const _Float16* src = Bg + (size_t)(k0 + kk) * OUT_ + ns;
#pragma unroll
                for (int j = 0; j < 8; ++j) Bs[ns + j][kk] = src[j];
            }
            __syncthreads();
            f16x8 a = *(const f16x8*)&As[wave * 16 + lm][q * 8];
#pragma unroll
            for (int c4 = 0; c4 < 4; ++c4) {
                f16x8 bb = *(const f16x8*)&Bs[c4 * 16 + lm][q * 8];
                acc[c4] = __builtin_amdgcn_mfma_f32_16x16x32_f16(a, bb, acc[c4], 0, 0, 0);
            }
            __syncthreads();
        }
#pragma unroll
        for (int c4 = 0; c4 < 4; ++c4)
#pragma unroll
            for (int g = 0; g < 4; ++g) mx[c4][g] = fmaxf(mx[c4][g], acc[c4][g]);
    }
#pragma unroll
    for (int c4 = 0; c4 < 4; ++c4)
#pragma unroll
        for (int g = 0; g < 4; ++g) {
            int row = wave * 16 + (lane >> 4) * 4 + g;
            int col = c4 * 16 + lm;
            size_t pos = ((size_t)b * N_ + n0 + row) * OUT_ + o0 + col;
            float v = mx[c4][g];
            v = fmaxf(v, (float)HWb[2 * rstride + pos]);
            v = fmaxf(v, (float)HWb[5 * rstride + pos]);
            v = fmaxf(v, (float)HWb[6 * rstride + pos]);
            out[pos] = v + bias[((size_t)(n0 + row)) * OUT_ + o0 + col];
        }
}

// ========================================================================================
extern "C" void kernel_launch(void* const* d_in, const int* in_sizes, int n_in,
                              void* d_out, int out_size, void* d_ws, size_t ws_size,
                              hipStream_t stream) {
    const float* feat = (const float*)d_in[0];
    const float* A1   = (const float*)d_in[1];
    const float* A2   = (const float*)d_in[2];
    const float* W    = (const float*)d_in[3];
    const float* We   = (const float*)d_in[4];
    const float* bias = (const float*)d_in[5];
    float* out = (float*)d_out;

    // fast-path ws layout (bytes) — HWN merged to 4 MB HWNmax, total ~57 MB
    const size_t OFF_CB   = 0;          //   8 KB
    const size_t OFF_WT   = 8192;       // 896 KB
    const size_t OFF_FE   = 1048576;    //   4 MB
    const size_t OFF_HWT  = 5242880;    //  16 MB
    const size_t OFF_HWNM = 22020096;   //   4 MB
    const size_t OFF_AHW  = 26214400;   //  32 MB (2 K-halves)
    const size_t WS_NEEDED = 59768832;

    if (ws_size >= WS_NEEDED) {
        float*    cbp  = (float*)((char*)d_ws + OFF_CB);
        _Float16* WTp  = (_Float16*)((char*)d_ws + OFF_WT);
        _Float16* Fe   = (_Float16*)((char*)d_ws + OFF_FE);
        _Float16* HWT  = (_Float16*)((char*)d_ws + OFF_HWT);
        _Float16* HWNm = (_Float16*)((char*)d_ws + OFF_HWNM);
        _Float16* AHW  = (_Float16*)((char*)d_ws + OFF_AHW);

        prep_kernel<<<2823, 256, 0, stream>>>(W, We, feat, cbp, WTp, Fe);
        hw7_kernel<<<640, 256, 0, stream>>>(Fe, WTp, cbp, HWT, HWNm);
        p2_kernel<<<1024, 256, 0, stream>>>(A1, A2, HWT, AHW);
        max_kernel<<<1024, 256, 0, stream>>>(AHW, HWNm, bias, out);
    } else {
        // round-1 fallback
        float* cb = (float*)d_ws;
        _Float16* HWb = (_Float16*)((char*)d_ws + 8192);
        cbias_kernel<<<7, 256, 0, stream>>>(W, We, cb);
        hw_kernel<<<dim3(128, 28), 256, 0, stream>>>(feat, W, cb, HWb);
        agg_kernel<<<dim3(4, 16, 8), 256, 0, stream>>>(A1, A2, HWb, bias, out);
    }
}

// Round 5
// 174.445 us; speedup vs baseline: 1.0468x; 1.0468x over previous
//
#include <hip/hip_runtime.h>
#include <hip/hip_bf16.h>

#define B_ 8
#define N_ 1024
#define F_ 256
#define OUT_ 256
#define REL_ 16
#define NADJ_ 7

typedef __attribute__((ext_vector_type(8))) _Float16 f16x8;
typedef __attribute__((ext_vector_type(4))) _Float16 f16x4;
typedef __attribute__((ext_vector_type(4))) float f32x4;

__device__ __forceinline__ void gll16(const _Float16* g, _Float16* l) {
    __builtin_amdgcn_global_load_lds(
        (const __attribute__((address_space(1))) void*)g,
        (__attribute__((address_space(3))) void*)l, 16, 0, 0);
}

__device__ __forceinline__ f16x8 cvt8(float4 a, float4 b) {
    return f16x8{(_Float16)a.x, (_Float16)a.y, (_Float16)a.z, (_Float16)a.w,
                 (_Float16)b.x, (_Float16)b.y, (_Float16)b.z, (_Float16)b.w};
}

#define MEMPIN() asm volatile("" ::: "memory")

// perm order: rr 0..3 = r{0,1,3,4} (real adjacency), 4..6 = r{2,5,6} (identity adjacency)
__constant__ const int c_perm[7] = {0, 1, 3, 4, 2, 5, 6};

// ---------------- prep: cbias (blocks 0..6) | transW (7..1798) | cvt feat (1799..2822) ---
__global__ __launch_bounds__(256) void prep_kernel(const float* __restrict__ W,
                                                   const float* __restrict__ We,
                                                   const float* __restrict__ feat,
                                                   float* __restrict__ cb,
                                                   _Float16* __restrict__ WTp,
                                                   _Float16* __restrict__ Fe) {
    int bid = blockIdx.x, tid = threadIdx.x;
    if (bid < 7) {
        int idx = bid * 256 + tid;
        int j = idx / OUT_, o = idx % OUT_;
        int r = c_perm[j];
        const float* Wr = W + (size_t)r * (F_ + REL_) * OUT_;
        float s = 0.f;
#pragma unroll
        for (int d = 0; d < REL_; ++d) s += We[r * REL_ + d] * Wr[(F_ + d) * OUT_ + o];
        cb[idx] = s;
    } else if (bid < 1799) {
        int idx = (bid - 7) * 256 + tid;  // 7*65536 total
        int j = idx >> 16, rem = idx & 65535, o = rem >> 8, f = rem & 255;
        int r = c_perm[j];
        WTp[idx] = (_Float16)W[((size_t)r * (F_ + REL_) + f) * OUT_ + o];
    } else {
        int i = (bid - 1799) * 256 + tid;  // 262144 groups of 8
        size_t base = (size_t)i * 8;
        float4 a = *(const float4*)(feat + base);
        float4 b = *(const float4*)(feat + base + 4);
        *(f16x8*)(Fe + base) = cvt8(a, b);
    }
}

// ======= hw7: 7 HW GEMMs, 3-stage pipelined gll16 staging.
// Invariant: counted vmcnt proving stage-ns landed comes BEFORE the s_barrier that
// publishes it (vmcnt is per-wave; the barrier is what makes it cross-wave).
// z<4: HWT[z][o][m] = (Fe @ W[z])^T + cb ; z>=4: HWN[z-4][m][o] = Fe @ W[z] + cb.
__global__ __launch_bounds__(256) void hw7_kernel(const _Float16* __restrict__ Fe,
                                                  const _Float16* __restrict__ WTp,
                                                  const float* __restrict__ cb,
                                                  _Float16* __restrict__ HWT,
                                                  _Float16* __restrict__ HWN) {
    __shared__ _Float16 S[3 * 8192];  // stage st: As = S+st*8192, Bs = As+4096 (BK=32)
    const int bid = blockIdx.x, tid = threadIdx.x;
    const int z = bid / 128, rem = bid % 128, bx = rem & 63, by = rem >> 6;
    const bool tr = (z < 4);
    const _Float16* A  = tr ? (WTp + (size_t)z * 65536) : Fe;
    const _Float16* Bt = tr ? Fe : (WTp + (size_t)z * 65536);
    const int m0 = (tr ? by : bx) * 128;
    const int n0 = (tr ? bx : by) * 128;
    const int wave = tid >> 6, lane = tid & 63, lm = lane & 15, q = lane >> 4;
    const int wr = (wave >> 1) * 64, wc = (wave & 1) * 64;
    const int srow = tid >> 2, sk = (tid & 3) * 8;
    const _Float16* ga0 = A + (size_t)(m0 + srow) * F_ + sk;
    const _Float16* ga1 = ga0 + (size_t)64 * F_;
    const _Float16* gb0 = Bt + (size_t)(n0 + srow) * F_ + sk;
    const _Float16* gb1 = gb0 + (size_t)64 * F_;

    f32x4 acc[4][4] = {};
    const int NT = 8;

    // prologue: prime stages 0 and 1; wait stage-0 BEFORE barrier
    {
        gll16(ga0, S + tid * 8);
        gll16(ga1, S + 2048 + tid * 8);
        gll16(gb0, S + 4096 + tid * 8);
        gll16(gb1, S + 6144 + tid * 8);
        MEMPIN();
        gll16(ga0 + 32, S + 8192 + tid * 8);
        gll16(ga1 + 32, S + 8192 + 2048 + tid * 8);
        gll16(gb0 + 32, S + 8192 + 4096 + tid * 8);
        gll16(gb1 + 32, S + 8192 + 6144 + tid * 8);
        asm volatile("s_waitcnt vmcnt(4)" ::: "memory");  // stage-0 landed (mine)
        __builtin_amdgcn_s_barrier();                     // now everyone's stage-0 landed
    }
    int cs = 0, ns = 1, fs = 2;
    for (int t = 0; t < NT; ++t) {
        if (t + 2 < NT) {
            const int k = (t + 2) * 32;
            _Float16* sb = S + fs * 8192;
            gll16(ga0 + k, sb + tid * 8);
            gll16(ga1 + k, sb + 2048 + tid * 8);
            gll16(gb0 + k, sb + 4096 + tid * 8);
            gll16(gb1 + k, sb + 6144 + tid * 8);
        }
        {
            const _Float16* Au = S + cs * 8192;
            const _Float16* Bu = Au + 4096;
            f16x8 af[4], bf[4];
#pragma unroll
            for (int i = 0; i < 4; ++i) af[i] = *(const f16x8*)(Au + (wr + i * 16 + lm) * 32 + q * 8);
#pragma unroll
            for (int j = 0; j < 4; ++j) bf[j] = *(const f16x8*)(Bu + (wc + j * 16 + lm) * 32 + q * 8);
            __builtin_amdgcn_s_setprio(1);
#pragma unroll
            for (int i = 0; i < 4; ++i)
#pragma unroll
                for (int j = 0; j < 4; ++j)
                    acc[i][j] = __builtin_amdgcn_mfma_f32_16x16x32_f16(af[i], bf[j], acc[i][j], 0, 0, 0);
            __builtin_amdgcn_s_setprio(0);
        }
        if (t + 1 < NT) {
            // prove stage-ns (issued at t-1) landed for THIS wave, then publish via barrier
            if (t + 2 < NT) asm volatile("s_waitcnt vmcnt(4)" ::: "memory");
            else            asm volatile("s_waitcnt vmcnt(0)" ::: "memory");
            __builtin_amdgcn_s_barrier();
        }
        int tmp = cs; cs = ns; ns = fs; fs = tmp;
    }
    const float* cbz = cb + (size_t)z * 256;
    if (tr) {
        _Float16* C = HWT + (size_t)z * ((size_t)256 * 8192);
#pragma unroll
        for (int i = 0; i < 4; ++i)
#pragma unroll
            for (int j = 0; j < 4; ++j)
#pragma unroll
                for (int g = 0; g < 4; ++g) {
                    int row = wr + i * 16 + q * 4 + g;   // o
                    int col = wc + j * 16 + lm;          // m
                    float v = acc[i][j][g] + cbz[m0 + row];
                    C[(size_t)(m0 + row) * 8192 + (n0 + col)] = (_Float16)v;
                }
    } else {
        _Float16* C = HWN + (size_t)(z - 4) * ((size_t)8192 * 256);
#pragma unroll
        for (int i = 0; i < 4; ++i)
#pragma unroll
            for (int j = 0; j < 4; ++j)
#pragma unroll
                for (int g = 0; g < 4; ++g) {
                    int row = wr + i * 16 + q * 4 + g;   // m
                    int col = wc + j * 16 + lm;          // o
                    float v = acc[i][j][g] + cbz[n0 + col];
                    C[(size_t)(m0 + row) * 256 + (n0 + col)] = (_Float16)v;
                }
    }
}

// ======= phase2: AHW[rr][b][n][o] = A_rr[b] @ HWT[rr][:, b*1024:+1024]^T =======
// Grid 512, 128x128 tiles, K=1024, BK=32, 3-stage LDS pipeline.
// iter t: [ds_write A ns from regs] [load A regs t+2; gll16 B t+2] [MFMA cs]
//         [vmcnt(6): B-ns landed] [lgkmcnt(0): A-ns visible] [s_barrier]   (wait BEFORE barrier)
// XCD remap: all 4 rr of one b on one XCD (A1[b],A2[b],B strips L2/L3-shared).
// As layout: element (m,k) at As[st*4096 + m*32 + (k ^ (((m>>4)&3)<<3))].
__global__ __launch_bounds__(256) void p2_kernel(const float* __restrict__ A1,
                                                 const float* __restrict__ A2,
                                                 const _Float16* __restrict__ HWT,
                                                 _Float16* __restrict__ AHW) {
    __shared__ _Float16 As[3 * 4096];
    __shared__ _Float16 Bs[3 * 4096];
    const int d = blockIdx.x;
    const int xcd = d & 7, slot = d >> 3;           // 64 slots per XCD
    const int zz = xcd + 8 * (slot >> 4);           // rr*8+b ; b == xcd
    const int member = (slot >> 3) & 1;             // o-tile
    const int mt = slot & 7;                        // m-tile
    const int rr = zz >> 3, b = zz & 7;

    const size_t slab = (size_t)B_ * N_ * OUT_;
    const _Float16* Bt = HWT + (size_t)rr * (256 * 8192) + (size_t)b * 1024;
    _Float16* C = AHW + (size_t)rr * slab + (size_t)b * (N_ * OUT_);
    const int m0 = mt * 128, n0 = member * 128;
    const int tid = threadIdx.x;
    const int wave = tid >> 6, lane = tid & 63, lm = lane & 15, q = lane >> 4;
    const int wr = (wave >> 1) * 64, wc = (wave & 1) * 64;
    const int srow = tid >> 2, sk = (tid & 3) * 8;
    const _Float16* gb0 = Bt + (size_t)(n0 + srow) * 8192 + sk;
    const _Float16* gb1 = gb0 + (size_t)64 * 8192;

    const float* Ag = ((rr & 1) ? A2 : A1) + (size_t)b * N_ * N_;
    f32x4 acc[4][4] = {};
    const int NT = 32;

    auto mfma_step = [&](int st) {
        const _Float16* Au = As + st * 4096;
        const _Float16* Bu = Bs + st * 4096;
        f16x8 af[4], bf[4];
#pragma unroll
        for (int i = 0; i < 4; ++i)
            af[i] = *(const f16x8*)(Au + (wr + i * 16 + lm) * 32 + ((q ^ i) * 8));
#pragma unroll
        for (int j = 0; j < 4; ++j)
            bf[j] = *(const f16x8*)(Bu + (wc + j * 16 + lm) * 32 + q * 8);
        __builtin_amdgcn_s_setprio(1);
#pragma unroll
        for (int i = 0; i < 4; ++i)
#pragma unroll
            for (int j = 0; j < 4; ++j)
                acc[i][j] = __builtin_amdgcn_mfma_f32_16x16x32_f16(af[i], bf[j], acc[i][j], 0, 0, 0);
        __builtin_amdgcn_s_setprio(0);
    };

    if (rr < 2) {
        // straight: As[m][k] = Ag[m0+m][t*32+k]
        const float* Ag0 = Ag + (size_t)(m0 + srow) * N_ + sk;
        const float* Ag1 = Ag0 + (size_t)64 * N_;
        const int sx = ((tid & 3) ^ ((tid >> 6) & 3)) * 8;
        float4 p0, p1, p2, p3;
        {   // prologue: A s0 via regs+ds_write, B s0 gll16; A regs s1; B s1 gll16
            float4 q0 = *(const float4*)(Ag0);
            float4 q1 = *(const float4*)(Ag0 + 4);
            float4 q2 = *(const float4*)(Ag1);
            float4 q3 = *(const float4*)(Ag1 + 4);
            *(f16x8*)(As + srow * 32 + sx) = cvt8(q0, q1);
            *(f16x8*)(As + 2048 + srow * 32 + sx) = cvt8(q2, q3);
            MEMPIN();
            gll16(gb0, Bs + tid * 8);
            gll16(gb1, Bs + 2048 + tid * 8);
            MEMPIN();
            p0 = *(const float4*)(Ag0 + 32);
            p1 = *(const float4*)(Ag0 + 36);
            p2 = *(const float4*)(Ag1 + 32);
            p3 = *(const float4*)(Ag1 + 36);
            MEMPIN();
            gll16(gb0 + 32, Bs + 4096 + tid * 8);
            gll16(gb1 + 32, Bs + 4096 + 2048 + tid * 8);
            asm volatile("s_waitcnt vmcnt(6)" ::: "memory");   // B s0 landed (mine)
            asm volatile("s_waitcnt lgkmcnt(0)" ::: "memory"); // A s0 visible
            __builtin_amdgcn_s_barrier();
        }
        int cs = 0, ns = 1, fs = 2;
        for (int t = 0; t < NT; ++t) {
            if (t + 1 < NT) {   // A stage ns from P (loaded last iter; compiler waits P)
                _Float16* la = As + ns * 4096 + srow * 32 + sx;
                *(f16x8*)(la) = cvt8(p0, p1);
                *(f16x8*)(la + 2048) = cvt8(p2, p3);
            }
            MEMPIN();
            if (t + 2 < NT) {
                const int k2 = (t + 2) * 32;
                p0 = *(const float4*)(Ag0 + k2);
                p1 = *(const float4*)(Ag0 + k2 + 4);
                p2 = *(const float4*)(Ag1 + k2);
                p3 = *(const float4*)(Ag1 + k2 + 4);
                MEMPIN();
                gll16(gb0 + k2, Bs + fs * 4096 + tid * 8);
                gll16(gb1 + k2, Bs + fs * 4096 + 2048 + tid * 8);
            }
            mfma_step(cs);
            if (t + 1 < NT) {
                // prove B-ns (gll16 issued at t-1) landed, publish A-ns ds_writes, THEN barrier
                if (t + 2 < NT) asm volatile("s_waitcnt vmcnt(6)" ::: "memory");
                else            asm volatile("s_waitcnt vmcnt(0)" ::: "memory");
                asm volatile("s_waitcnt lgkmcnt(0)" ::: "memory");
                __builtin_amdgcn_s_barrier();
            }
            int tmp = cs; cs = ns; ns = fs; fs = tmp;
        }
    } else {
        // transposed: As[m][k] = Ag[t*32+kk4+i][m0+m]; coalesced k-row reads, b64 scatter.
        const int kk4 = (tid >> 5) * 4;          // 0..28
        const int ms4 = (tid & 31) * 4;          // 0..124
        const int tsw = ((ms4 >> 4) & 3) << 3;
        const int wof = ms4 * 32 + (kk4 ^ tsw);
        const float* gA0 = Ag + (size_t)kk4 * N_ + m0 + ms4;
        float4 r0, r1, r2, r3;
        {   // prologue
            float4 q0 = *(const float4*)(gA0);
            float4 q1 = *(const float4*)(gA0 + N_);
            float4 q2 = *(const float4*)(gA0 + 2 * N_);
            float4 q3 = *(const float4*)(gA0 + 3 * N_);
            _Float16* wp = As + wof;
            *(f16x4*)(wp + 0 * 32) = f16x4{(_Float16)q0.x, (_Float16)q1.x, (_Float16)q2.x, (_Float16)q3.x};
            *(f16x4*)(wp + 1 * 32) = f16x4{(_Float16)q0.y, (_Float16)q1.y, (_Float16)q2.y, (_Float16)q3.y};
            *(f16x4*)(wp + 2 * 32) = f16x4{(_Float16)q0.z, (_Float16)q1.z, (_Float16)q2.z, (_Float16)q3.z};
            *(f16x4*)(wp + 3 * 32) = f16x4{(_Float16)q0.w, (_Float16)q1.w, (_Float16)q2.w, (_Float16)q3.w};
            MEMPIN();
            gll16(gb0, Bs + tid * 8);
            gll16(gb1, Bs + 2048 + tid * 8);
            MEMPIN();
            const float* p = gA0 + (size_t)32 * N_;
            r0 = *(const float4*)(p);
            r1 = *(const float4*)(p + N_);
            r2 = *(const float4*)(p + 2 * N_);
            r3 = *(const float4*)(p + 3 * N_);
            MEMPIN();
            gll16(gb0 + 32, Bs + 4096 + tid * 8);
            gll16(gb1 + 32, Bs + 4096 + 2048 + tid * 8);
            asm volatile("s_waitcnt vmcnt(6)" ::: "memory");
            asm volatile("s_waitcnt lgkmcnt(0)" ::: "memory");
            __builtin_amdgcn_s_barrier();
        }
        const float* gp = gA0 + (size_t)64 * N_;
        int cs = 0, ns = 1, fs = 2;
        for (int t = 0; t < NT; ++t) {
            if (t + 1 < NT) {
                _Float16* wp = As + ns * 4096 + wof;
                *(f16x4*)(wp + 0 * 32) = f16x4{(_Float16)r0.x, (_Float16)r1.x, (_Float16)r2.x, (_Float16)r3.x};
                *(f16x4*)(wp + 1 * 32) = f16x4{(_Float16)r0.y, (_Float16)r1.y, (_Float16)r2.y, (_Float16)r3.y};
                *(f16x4*)(wp + 2 * 32) = f16x4{(_Float16)r0.z, (_Float16)r1.z, (_Float16)r2.z, (_Float16)r3.z};
                *(f16x4*)(wp + 3 * 32) = f16x4{(_Float16)r0.w, (_Float16)r1.w, (_Float16)r2.w, (_Float16)r3.w};
            }
            MEMPIN();
            if (t + 2 < NT) {
                r0 = *(const float4*)(gp);
                r1 = *(const float4*)(gp + N_);
                r2 = *(const float4*)(gp + 2 * N_);
                r3 = *(const float4*)(gp + 3 * N_);
                gp += (size_t)32 * N_;
                MEMPIN();
                const int k2 = (t + 2) * 32;
                gll16(gb0 + k2, Bs + fs * 4096 + tid * 8);
                gll16(gb1 + k2, Bs + fs * 4096 + 2048 + tid * 8);
            }
            mfma_step(cs);
            if (t + 1 < NT) {
                if (t + 2 < NT) asm volatile("s_waitcnt vmcnt(6)" ::: "memory");
                else            asm volatile("s_waitcnt vmcnt(0)" ::: "memory");
                asm volatile("s_waitcnt lgkmcnt(0)" ::: "memory");
                __builtin_amdgcn_s_barrier();
            }
            int tmp = cs; cs = ns; ns = fs; fs = tmp;
        }
    }
#pragma unroll
    for (int i = 0; i < 4; ++i)
#pragma unroll
        for (int j = 0; j < 4; ++j)
#pragma unroll
            for (int g = 0; g < 4; ++g) {
                int row = wr + i * 16 + q * 4 + g;
                int col = wc + j * 16 + lm;
                C[(size_t)(m0 + row) * 256 + (n0 + col)] = (_Float16)acc[i][j][g];
            }
}

// ======= final: out = max(AHW[0..3], HWN[0..2]) + bias =======
__global__ __launch_bounds__(256) void max_kernel(const _Float16* __restrict__ AHW,
                                                  const _Float16* __restrict__ HWN,
                                                  const float* __restrict__ bias,
                                                  float* __restrict__ out) {
    size_t i = ((size_t)blockIdx.x * 256 + threadIdx.x) * 8;
    const size_t slab = (size_t)B_ * N_ * OUT_;
    float m[8];
    f16x8 v = *(const f16x8*)(AHW + i);
#pragma unroll
    for (int e = 0; e < 8; ++e) m[e] = (float)v[e];
#pragma unroll
    for (int rr = 1; rr < 4; ++rr) {
        f16x8 w = *(const f16x8*)(AHW + rr * slab + i);
#pragma unroll
        for (int e = 0; e < 8; ++e) m[e] = fmaxf(m[e], (float)w[e]);
    }
#pragma unroll
    for (int j = 0; j < 3; ++j) {
        f16x8 w = *(const f16x8*)(HWN + j * slab + i);
#pragma unroll
        for (int e = 0; e < 8; ++e) m[e] = fmaxf(m[e], (float)w[e]);
    }
    size_t bidx = i & ((size_t)N_ * OUT_ - 1);
    float4 b0 = *(const float4*)(bias + bidx);
    float4 b1 = *(const float4*)(bias + bidx + 4);
    float4 o0 = {m[0] + b0.x, m[1] + b0.y, m[2] + b0.z, m[3] + b0.w};
    float4 o1 = {m[4] + b1.x, m[5] + b1.y, m[6] + b1.z, m[7] + b1.w};
    *(float4*)(out + i) = o0;
    *(float4*)(out + i + 4) = o1;
}

// ======================= round-1 fallback path (ws too small) ===========================
__global__ void cbias_kernel(const float* __restrict__ W, const float* __restrict__ We,
                             float* __restrict__ c) {
    int idx = blockIdx.x * 256 + threadIdx.x;
    if (idx >= NADJ_ * OUT_) return;
    int r = idx / OUT_, o = idx % OUT_;
    const float* Wr = W + (size_t)r * (F_ + REL_) * OUT_;
    float s = 0.f;
#pragma unroll
    for (int d = 0; d < REL_; ++d) s += We[r * REL_ + d] * Wr[(F_ + d) * OUT_ + o];
    c[idx] = s;
}

__global__ __launch_bounds__(256) void hw_kernel(const float* __restrict__ feat,
                                                 const float* __restrict__ W,
                                                 const float* __restrict__ cb,
                                                 _Float16* __restrict__ HWb) {
    __shared__ _Float16 As[64][32];
    __shared__ _Float16 Bs[64][32];
    const int mt = blockIdx.x, ct = blockIdx.y;
    const int tid = threadIdx.x, wave = tid >> 6, lane = tid & 63;
    const int r = (ct * 64) / OUT_;
    const int o0 = (ct * 64) % OUT_;
    const float* Bg = W + (size_t)r * (F_ + REL_) * OUT_ + o0;
    const int m0 = mt * 64;
    const int lm = lane & 15, q = lane >> 4;
    f32x4 acc[4] = {};
    for (int k0 = 0; k0 < F_; k0 += 32) {
        {
            int seg = (tid & 3) * 8, m = tid >> 2;
            const float* src = feat + (size_t)(m0 + m) * F_ + k0 + seg;
#pragma unroll
            for (int j = 0; j < 8; ++j) As[m][seg + j] = (_Float16)src[j];
        }
        {
            int kk = tid >> 3, ns = (tid & 7) * 8;
            const float* src = Bg + (size_t)(k0 + kk) * OUT_ + ns;
#pragma unroll
            for (int j = 0; j < 8; ++j) Bs[ns + j][kk] = (_Float16)src[j];
        }
        __syncthreads();
        f16x8 a = *(const f16x8*)&As[wave * 16 + lm][q * 8];
#pragma unroll
        for (int c4 = 0; c4 < 4; ++c4) {
            f16x8 b = *(const f16x8*)&Bs[c4 * 16 + lm][q * 8];
            acc[c4] = __builtin_amdgcn_mfma_f32_16x16x32_f16(a, b, acc[c4], 0, 0, 0);
        }
        __syncthreads();
    }
#pragma unroll
    for (int c4 = 0; c4 < 4; ++c4)
#pragma unroll
        for (int g = 0; g < 4; ++g) {
            int row = wave * 16 + (lane >> 4) * 4 + g;
            int col = c4 * 16 + lm;
            float v = acc[c4][g] + cb[r * OUT_ + o0 + col];
            HWb[((size_t)r * B_ * N_ + m0 + row) * OUT_ + o0 + col] = (_Float16)v;
        }
}

__global__ __launch_bounds__(256) void agg_kernel(const float* __restrict__ A1,
                                                  const float* __restrict__ A2,
                                                  const _Float16* __restrict__ HWb,
                                                  const float* __restrict__ bias,
                                                  float* __restrict__ out) {
    __shared__ _Float16 As[64][32];
    __shared__ _Float16 Bs[64][32];
    const int b = blockIdx.z, nt = blockIdx.y, ot = blockIdx.x;
    const int tid = threadIdx.x, wave = tid >> 6, lane = tid & 63;
    const int n0 = nt * 64, o0 = ot * 64;
    const int lm = lane & 15, q = lane >> 4;
    const size_t rstride = (size_t)B_ * N_ * OUT_;
    f32x4 mx[4];
#pragma unroll
    for (int i = 0; i < 4; ++i) mx[i] = f32x4{-1e30f, -1e30f, -1e30f, -1e30f};
#pragma unroll 1
    for (int rr = 0; rr < 4; ++rr) {
        const float* Ag = ((rr & 1) ? A2 : A1) + (size_t)b * N_ * N_;
        const bool tr = (rr >= 2);
        const int r = (rr < 2) ? rr : rr + 1;
        const _Float16* Bg = HWb + (size_t)r * rstride + (size_t)b * N_ * OUT_ + o0;
        f32x4 acc[4] = {};
        for (int k0 = 0; k0 < N_; k0 += 32) {
            if (!tr) {
                int seg = (tid & 3) * 8, m = tid >> 2;
                const float* src = Ag + (size_t)(n0 + m) * N_ + k0 + seg;
#pragma unroll
                for (int j = 0; j < 8; ++j) As[m][seg + j] = (_Float16)src[j];
            } else {
                int kk = tid >> 3, ms = (tid & 7) * 8;
                const float* src = Ag + (size_t)(k0 + kk) * N_ + n0 + ms;
#pragma unroll
                for (int j = 0; j < 8; ++j) As[ms + j][kk] = (_Float16)src[j];
            }
            {
                int kk = tid >> 3, ns = (tid & 7) * 8;
                const _Float16* src = Bg + (size_t)(k0 + kk) * OUT_ + ns;
#pragma unroll
                for (int j = 0; j < 8; ++j) Bs[ns + j][kk] = src[j];
            }
            __syncthreads();
            f16x8 a = *(const f16x8*)&As[wave * 16 + lm][q * 8];
#pragma unroll
            for (int c4 = 0; c4 < 4; ++c4) {
                f16x8 bb = *(const f16x8*)&Bs[c4 * 16 + lm][q * 8];
                acc[c4] = __builtin_amdgcn_mfma_f32_16x16x32_f16(a, bb, acc[c4], 0, 0, 0);
            }
            __syncthreads();
        }
#pragma unroll
        for (int c4 = 0; c4 < 4; ++c4)
#pragma unroll
            for (int g = 0; g < 4; ++g) mx[c4][g] = fmaxf(mx[c4][g], acc[c4][g]);
    }
#pragma unroll
    for (int c4 = 0; c4 < 4; ++c4)
#pragma unroll
        for (int g = 0; g < 4; ++g) {
            int row = wave * 16 + (lane >> 4) * 4 + g;
            int col = c4 * 16 + lm;
            size_t pos = ((size_t)b * N_ + n0 + row) * OUT_ + o0 + col;
            float v = mx[c4][g];
            v = fmaxf(v, (float)HWb[2 * rstride + pos]);
            v = fmaxf(v, (float)HWb[5 * rstride + pos]);
            v = fmaxf(v, (float)HWb[6 * rstride + pos]);
            out[pos] = v + bias[((size_t)(n0 + row)) * OUT_ + o0 + col];
        }
}

// ========================================================================================
extern "C" void kernel_launch(void* const* d_in, const int* in_sizes, int n_in,
                              void* d_out, int out_size, void* d_ws, size_t ws_size,
                              hipStream_t stream) {
    const float* feat = (const float*)d_in[0];
    const float* A1   = (const float*)d_in[1];
    const float* A2   = (const float*)d_in[2];
    const float* W    = (const float*)d_in[3];
    const float* We   = (const float*)d_in[4];
    const float* bias = (const float*)d_in[5];
    float* out = (float*)d_out;

    // fast-path ws layout (bytes) — total 51.4 MB
    const size_t OFF_CB   = 0;          //   8 KB
    const size_t OFF_WT   = 8192;       // 896 KB
    const size_t OFF_FE   = 1048576;    //   4 MB
    const size_t OFF_HWT  = 5242880;    //  16 MB
    const size_t OFF_HWN  = 22020096;   //  12 MB
    const size_t OFF_AHW  = 34603008;   //  16 MB
    const size_t WS_NEEDED = 51380224;

    if (ws_size >= WS_NEEDED) {
        float*    cbp = (float*)((char*)d_ws + OFF_CB);
        _Float16* WTp = (_Float16*)((char*)d_ws + OFF_WT);
        _Float16* Fe  = (_Float16*)((char*)d_ws + OFF_FE);
        _Float16* HWT = (_Float16*)((char*)d_ws + OFF_HWT);
        _Float16* HWN = (_Float16*)((char*)d_ws + OFF_HWN);
        _Float16* AHW = (_Float16*)((char*)d_ws + OFF_AHW);

        prep_kernel<<<2823, 256, 0, stream>>>(W, We, feat, cbp, WTp, Fe);
        hw7_kernel<<<896, 256, 0, stream>>>(Fe, WTp, cbp, HWT, HWN);
        p2_kernel<<<512, 256, 0, stream>>>(A1, A2, HWT, AHW);
        max_kernel<<<1024, 256, 0, stream>>>(AHW, HWN, bias, out);
    } else {
        // round-1 fallback
        float* cb = (float*)d_ws;
        _Float16* HWb = (_Float16*)((char*)d_ws + 8192);
        cbias_kernel<<<7, 256, 0, stream>>>(W, We, cb);
        hw_kernel<<<dim3(128, 28), 256, 0, stream>>>(feat, W, cb, HWb);
        agg_kernel<<<dim3(4, 16, 8), 256, 0, stream>>>(A1, A2, HWb, bias, out);
    }
}